// Round 14
// baseline (461.818 us; speedup 1.0000x reference)
//
#include <hip/hip_runtime.h>
#include <math.h>

#define NN 100000
#define NE 1600000
#define D 64
#define DE 32
#define NB_SCAN ((NN + 255) / 256)   // 391

typedef __attribute__((ext_vector_type(8))) short short8;
typedef __attribute__((ext_vector_type(4))) float f32x4;

__device__ __forceinline__ int rfl(int v){ return __builtin_amdgcn_readfirstlane(v); }

#define LEAKY(v) fmaxf((v), 0.2f*(v))

__device__ __forceinline__ unsigned short f2bf(float x){
  unsigned u = __float_as_uint(x);
  unsigned r = (u + 0x7fffu + ((u >> 16) & 1u)) >> 16;
  return (unsigned short)r;
}
__device__ __forceinline__ float bf2f(unsigned short b){
  return __uint_as_float(((unsigned)b) << 16);
}

// cursor doubles as deg accumulator
__global__ __launch_bounds__(256) void k_deg(const int* __restrict__ dst, int* __restrict__ cursor){
  int i = blockIdx.x*256 + threadIdx.x;
  if (i < NE) atomicAdd(&cursor[dst[i]], 1);
}

__global__ __launch_bounds__(256) void k_scan_a(const int* __restrict__ deg, int* __restrict__ bsum){
  __shared__ int sh[256];
  int tid = threadIdx.x;
  int i = blockIdx.x*256 + tid;
  sh[tid] = (i < NN) ? deg[i] : 0;
  __syncthreads();
  for (int s = 128; s > 0; s >>= 1){
    if (tid < s) sh[tid] += sh[tid+s];
    __syncthreads();
  }
  if (tid == 0) bsum[blockIdx.x] = sh[0];
}

__global__ __launch_bounds__(512) void k_scan_b(int* __restrict__ bsum, int* __restrict__ rowptr){
  __shared__ int tmp[512];
  int tid = threadIdx.x;
  int v = (tid < NB_SCAN) ? bsum[tid] : 0;
  tmp[tid] = v;
  __syncthreads();
  for (int off = 1; off < 512; off <<= 1){
    int t = (tid >= off) ? tmp[tid-off] : 0;
    __syncthreads();
    tmp[tid] += t;
    __syncthreads();
  }
  if (tid < NB_SCAN) bsum[tid] = tmp[tid] - v;
  if (tid == 511) rowptr[NN] = tmp[511];
}

// reads cursor (=deg), writes rowptr and resets cursor to the exclusive offset
__global__ __launch_bounds__(256) void k_scan_c(const int* bsum, int* rowptr, int* cursor){
  __shared__ int tmp[256];
  int tid = threadIdx.x;
  int i = blockIdx.x*256 + tid;
  int v = (i < NN) ? cursor[i] : 0;
  tmp[tid] = v;
  __syncthreads();
  for (int off = 1; off < 256; off <<= 1){
    int t = (tid >= off) ? tmp[tid-off] : 0;
    __syncthreads();
    tmp[tid] += t;
    __syncthreads();
  }
  if (i < NN){
    int excl = tmp[tid] - v + bsum[blockIdx.x];
    rowptr[i] = excl;
    cursor[i] = excl;
  }
}

// slot[pos]=edge id of CSR slot, ssrc[pos]=src node of CSR slot
__global__ __launch_bounds__(256) void k_scatter(const int* __restrict__ srcp, const int* __restrict__ dstp,
                                                 int* __restrict__ cursor,
                                                 int* __restrict__ slot, int* __restrict__ ssrc){
  int i = blockIdx.x*256 + threadIdx.x;
  if (i < NE){
    int d = dstp[i];
    int pos = atomicAdd(&cursor[d], 1);
    slot[pos] = i;
    ssrc[pos] = srcp[i];
  }
}

// ea_csr[pos][*] = bf16(eattr[slot[pos]][*]). 8 threads per row: full-line
// random reads (consecutive threads cover one 128B row), coalesced bf16 writes.
__global__ __launch_bounds__(256) void k_perm(const int* __restrict__ slot,
                                              const float4* __restrict__ eattr4,
                                              ushort4* __restrict__ ea_csr4){
  int i = blockIdx.x*256 + threadIdx.x;
  if (i < NE*8){
    int e = i >> 3, c = i & 7;
    int se = slot[e];
    float4 v = eattr4[(size_t)se*8 + c];
    ushort4 o;
    o.x = f2bf(v.x); o.y = f2bf(v.y); o.z = f2bf(v.z); o.w = f2bf(v.w);
    ea_csr4[(size_t)e*8 + c] = o;
  }
}

// MFMA linear: xl[n][j] = bf16( b[j] + sum_k x[n][k]*W[k][j] ).
// Wave per 16-node tile (NN%16==0). A = 16 x-rows (coalesced float4 loads);
// B = W col-permuted (R11 recipe), K=64 = 2 chained MFMAs, C init = bias.
__global__ __launch_bounds__(256) void k_lin(const float* __restrict__ xin, const float* __restrict__ W,
                                             const float* __restrict__ b, unsigned short* __restrict__ xl){
  int lane = threadIdx.x & 63;
  int q = lane & 15, g = lane >> 4;
  int wid = blockIdx.x*(blockDim.x>>6) + (threadIdx.x>>6);
  int nw = gridDim.x*(blockDim.x>>6);
  short8 wb[2][4];
  #pragma unroll
  for (int kk = 0; kk < 2; ++kk)
    #pragma unroll
    for (int j = 0; j < 4; ++j)
      #pragma unroll
      for (int i = 0; i < 8; ++i)
        wb[kk][j][i] = (short)f2bf(W[(32*kk + 8*g + i)*D + 4*q + j]);
  float4 b4 = *(const float4*)(b + 4*q);
  for (int t0 = wid; t0 < NN/16; t0 += nw){
    int n0 = rfl(t0)*16;
    const float* xr = xin + (size_t)(n0 + q)*D + 8*g;
    float4 a0 = *(const float4*)(xr);
    float4 a1 = *(const float4*)(xr + 4);
    float4 a2 = *(const float4*)(xr + 32);
    float4 a3 = *(const float4*)(xr + 36);
    short8 af0, af1;
    af0[0]=(short)f2bf(a0.x); af0[1]=(short)f2bf(a0.y); af0[2]=(short)f2bf(a0.z); af0[3]=(short)f2bf(a0.w);
    af0[4]=(short)f2bf(a1.x); af0[5]=(short)f2bf(a1.y); af0[6]=(short)f2bf(a1.z); af0[7]=(short)f2bf(a1.w);
    af1[0]=(short)f2bf(a2.x); af1[1]=(short)f2bf(a2.y); af1[2]=(short)f2bf(a2.z); af1[3]=(short)f2bf(a2.w);
    af1[4]=(short)f2bf(a3.x); af1[5]=(short)f2bf(a3.y); af1[6]=(short)f2bf(a3.z); af1[7]=(short)f2bf(a3.w);
    f32x4 acc0 = {b4.x, b4.x, b4.x, b4.x};
    f32x4 acc1 = {b4.y, b4.y, b4.y, b4.y};
    f32x4 acc2 = {b4.z, b4.z, b4.z, b4.z};
    f32x4 acc3 = {b4.w, b4.w, b4.w, b4.w};
    acc0 = __builtin_amdgcn_mfma_f32_16x16x32_bf16(af0, wb[0][0], acc0, 0, 0, 0);
    acc1 = __builtin_amdgcn_mfma_f32_16x16x32_bf16(af0, wb[0][1], acc1, 0, 0, 0);
    acc2 = __builtin_amdgcn_mfma_f32_16x16x32_bf16(af0, wb[0][2], acc2, 0, 0, 0);
    acc3 = __builtin_amdgcn_mfma_f32_16x16x32_bf16(af0, wb[0][3], acc3, 0, 0, 0);
    acc0 = __builtin_amdgcn_mfma_f32_16x16x32_bf16(af1, wb[1][0], acc0, 0, 0, 0);
    acc1 = __builtin_amdgcn_mfma_f32_16x16x32_bf16(af1, wb[1][1], acc1, 0, 0, 0);
    acc2 = __builtin_amdgcn_mfma_f32_16x16x32_bf16(af1, wb[1][2], acc2, 0, 0, 0);
    acc3 = __builtin_amdgcn_mfma_f32_16x16x32_bf16(af1, wb[1][3], acc3, 0, 0, 0);
    #pragma unroll
    for (int i = 0; i < 4; ++i){
      ushort4 pk;
      pk.x = f2bf(acc0[i]); pk.y = f2bf(acc1[i]); pk.z = f2bf(acc2[i]); pk.w = f2bf(acc3[i]);
      *(ushort4*)(xl + (size_t)(n0 + 4*g + i)*D + 4*q) = pk;
    }
  }
}

// Fully fused per-destination layer: edge MLP (MFMA, ea_csr sequential bf16) +
// logit + softmax + aggregate. Wave per node; edges in tiles of 16.
__global__ __launch_bounds__(256) void k_node(const int* __restrict__ rowptr,
                                              const int* __restrict__ ssrc,
                                              const unsigned short* __restrict__ ea_csr,
                                              const float* __restrict__ We,
                                              const float* __restrict__ att,
                                              const unsigned short* __restrict__ xl,
                                              const float* __restrict__ bias,
                                              float* __restrict__ outp){
  int lane = threadIdx.x & 63;
  int q = lane & 15;          // A-row in tile / D col-group (dims 4q..4q+3)
  int g = lane >> 4;          // A/B k-group / D row-group (edges 4g..4g+3)
  int wid = blockIdx.x*(blockDim.x>>6) + (threadIdx.x>>6);
  int nw = gridDim.x*(blockDim.x>>6);
  // B fragments, column-permuted (R11-verified): wb[j][i] = We[(8g+i)][4q+j]
  short8 wb[4];
  #pragma unroll
  for (int j = 0; j < 4; ++j){
    #pragma unroll
    for (int i = 0; i < 8; ++i){
      wb[j][i] = (short)f2bf(We[(8*g + i)*D + 4*q + j]);
    }
  }
  float4 att4 = *(const float4*)(att + 4*q);
  float4 bi4  = *(const float4*)(bias + 4*q);
  for (int n0 = wid; n0 < NN; n0 += nw){
    int n = rfl(n0);
    int st = rowptr[n], en = rowptr[n+1];
    ushort4 xdu = *(const ushort4*)(xl + (size_t)n*D + 4*q);
    float xd0 = bf2f(xdu.x), xd1 = bf2f(xdu.y), xd2 = bf2f(xdu.z), xd3 = bf2f(xdu.w);
    float den = 0.f;
    float ac0=0.f, ac1=0.f, ac2=0.f, ac3=0.f;
    float ts0=0.f, ts1=0.f, ts2=0.f, ts3=0.f;
    for (int base = st; base < en; base += 16){
      int nb = en - base; if (nb > 16) nb = 16;
      // A fragment: CSR row base+q (clamped), k-slice 8g..8g+7 — sequential bf16
      int rrow = base + ((q < nb) ? q : (nb - 1));
      short8 a = *(const short8*)(ea_csr + (size_t)rrow*DE + 8*g);
      f32x4 d0={0.f,0.f,0.f,0.f}, d1={0.f,0.f,0.f,0.f}, d2={0.f,0.f,0.f,0.f}, d3={0.f,0.f,0.f,0.f};
      d0 = __builtin_amdgcn_mfma_f32_16x16x32_bf16(a, wb[0], d0, 0, 0, 0);
      d1 = __builtin_amdgcn_mfma_f32_16x16x32_bf16(a, wb[1], d1, 0, 0, 0);
      d2 = __builtin_amdgcn_mfma_f32_16x16x32_bf16(a, wb[2], d2, 0, 0, 0);
      d3 = __builtin_amdgcn_mfma_f32_16x16x32_bf16(a, wb[3], d3, 0, 0, 0);
      #pragma unroll
      for (int i = 0; i < 4; ++i){
        int eoff = 4*g + i;
        bool valid = (eoff < nb);
        int eidx = base + (valid ? eoff : 0);
        int si = ssrc[eidx];                                   // 16-lane broadcast
        ushort4 xu = *(const ushort4*)(xl + (size_t)si*D + 4*q);
        float x0=bf2f(xu.x), x1=bf2f(xu.y), x2=bf2f(xu.z), x3=bf2f(xu.w);
        float t0 = d0[i], t1 = d1[i], t2 = d2[i], t3 = d3[i];
        float part = att4.x*LEAKY(x0+xd0+t0);
        part = fmaf(att4.y, LEAKY(x1+xd1+t1), part);
        part = fmaf(att4.z, LEAKY(x2+xd2+t2), part);
        part = fmaf(att4.w, LEAKY(x3+xd3+t3), part);
        part += __shfl_xor(part, 1, 64);
        part += __shfl_xor(part, 2, 64);
        part += __shfl_xor(part, 4, 64);
        part += __shfl_xor(part, 8, 64);
        float c = valid ? part : -1e30f;
        float p = __expf(c);
        den += p;
        if (valid){ ts0 += t0; ts1 += t1; ts2 += t2; ts3 += t3; }
        ac0 = fmaf(p, x0, ac0); ac1 = fmaf(p, x1, ac1);
        ac2 = fmaf(p, x2, ac2); ac3 = fmaf(p, x3, ac3);
      }
    }
    // cross-group combine (different edges per group; same dims per q)
    #pragma unroll
    for (int off = 16; off <= 32; off <<= 1){
      den += __shfl_xor(den, off, 64);
      ac0 += __shfl_xor(ac0, off, 64); ac1 += __shfl_xor(ac1, off, 64);
      ac2 += __shfl_xor(ac2, off, 64); ac3 += __shfl_xor(ac3, off, 64);
      ts0 += __shfl_xor(ts0, off, 64); ts1 += __shfl_xor(ts1, off, 64);
      ts2 += __shfl_xor(ts2, off, 64); ts3 += __shfl_xor(ts3, off, 64);
    }
    // self loop: t_self = mean(t) by linearity; 0 for isolated nodes
    float inv = 1.f / fmaxf((float)(en - st), 1.f);
    float s0 = fmaf(ts0, inv, xd0 + xd0);
    float s1 = fmaf(ts1, inv, xd1 + xd1);
    float s2 = fmaf(ts2, inv, xd2 + xd2);
    float s3 = fmaf(ts3, inv, xd3 + xd3);
    float cs = att4.x*LEAKY(s0);
    cs = fmaf(att4.y, LEAKY(s1), cs);
    cs = fmaf(att4.z, LEAKY(s2), cs);
    cs = fmaf(att4.w, LEAKY(s3), cs);
    cs += __shfl_xor(cs, 1, 64);
    cs += __shfl_xor(cs, 2, 64);
    cs += __shfl_xor(cs, 4, 64);
    cs += __shfl_xor(cs, 8, 64);
    float ps = __expf(cs);
    den += ps;
    ac0 = fmaf(ps, xd0, ac0); ac1 = fmaf(ps, xd1, ac1);
    ac2 = fmaf(ps, xd2, ac2); ac3 = fmaf(ps, xd3, ac3);
    if (g == 0){
      float4 o;
      float dinv = 1.f / den;
      o.x = fmaf(ac0, dinv, bi4.x);
      o.y = fmaf(ac1, dinv, bi4.y);
      o.z = fmaf(ac2, dinv, bi4.z);
      o.w = fmaf(ac3, dinv, bi4.w);
      *(float4*)(outp + (size_t)n*D + 4*q) = o;
    }
  }
}

extern "C" void kernel_launch(void* const* d_in, const int* in_sizes, int n_in,
                              void* d_out, int out_size, void* d_ws, size_t ws_size,
                              hipStream_t stream){
  const float* x     = (const float*)d_in[0];
  const int*   ei    = (const int*)d_in[1];
  const float* eattr = (const float*)d_in[2];
  const float* W1    = (const float*)d_in[3];
  const float* b1    = (const float*)d_in[4];
  const float* We1   = (const float*)d_in[5];
  const float* att1  = (const float*)d_in[6];
  const float* bias1 = (const float*)d_in[7];
  const float* W2    = (const float*)d_in[8];
  const float* b2    = (const float*)d_in[9];
  const float* We2   = (const float*)d_in[10];
  const float* att2  = (const float*)d_in[11];
  const float* bias2 = (const float*)d_in[12];
  const int* srcp = ei;
  const int* dstp = ei + NE;
  float* out = (float*)d_out;

  char* p = (char*)d_ws;
  size_t off = 0;
  auto alloc = [&](size_t bytes)->char*{
    char* r = p + off; off = (off + bytes + 255) & ~(size_t)255; return r;
  };
  int* rowptr   = (int*)alloc((size_t)(NN+1)*4);
  int* cursor   = (int*)alloc((size_t)NN*4);       // also deg accumulator
  int* bsum     = (int*)alloc(512*4);
  int* slot     = (int*)alloc((size_t)NE*4);
  int* ssrc     = (int*)alloc((size_t)NE*4);
  unsigned short* xl = (unsigned short*)alloc((size_t)NN*D*2);  // bf16 rows
  float* h      = (float*)alloc((size_t)NN*D*4);
  unsigned short* ea_csr = (unsigned short*)alloc((size_t)NE*DE*2);  // 102.4 MB bf16

  hipMemsetAsync(cursor, 0, (size_t)NN*4, stream);
  k_deg     <<<(NE+255)/256, 256, 0, stream>>>(dstp, cursor);
  k_scan_a  <<<NB_SCAN, 256, 0, stream>>>(cursor, bsum);
  k_scan_b  <<<1, 512, 0, stream>>>(bsum, rowptr);
  k_scan_c  <<<NB_SCAN, 256, 0, stream>>>(bsum, rowptr, cursor);
  k_scatter <<<(NE+255)/256, 256, 0, stream>>>(srcp, dstp, cursor, slot, ssrc);
  k_perm    <<<(NE*8+255)/256, 256, 0, stream>>>(slot, (const float4*)eattr, (ushort4*)ea_csr);

  // layer 1
  k_lin <<<1600, 256, 0, stream>>>(x, W1, b1, xl);
  k_node<<<8192, 256, 0, stream>>>(rowptr, ssrc, ea_csr, We1, att1, xl, bias1, h);
  // layer 2
  k_lin <<<1600, 256, 0, stream>>>(h, W2, b2, xl);
  k_node<<<8192, 256, 0, stream>>>(rowptr, ssrc, ea_csr, We2, att2, xl, bias2, out);
}

// Round 15
// 367.214 us; speedup vs baseline: 1.2576x; 1.2576x over previous
//
#include <hip/hip_runtime.h>
#include <math.h>

#define NN 100000
#define NE 1600000
#define D 64
#define DE 32
#define NB_SCAN ((NN + 255) / 256)   // 391

typedef __attribute__((ext_vector_type(8))) short short8;
typedef __attribute__((ext_vector_type(4))) float f32x4;

__device__ __forceinline__ int rfl(int v){ return __builtin_amdgcn_readfirstlane(v); }

#define LEAKY(v) fmaxf((v), 0.2f*(v))

__device__ __forceinline__ unsigned short f2bf(float x){
  unsigned u = __float_as_uint(x);
  unsigned r = (u + 0x7fffu + ((u >> 16) & 1u)) >> 16;
  return (unsigned short)r;
}
__device__ __forceinline__ float bf2f(unsigned short b){
  return __uint_as_float(((unsigned)b) << 16);
}

// cursor doubles as deg accumulator
__global__ __launch_bounds__(256) void k_deg(const int* __restrict__ dst, int* __restrict__ cursor){
  int i = blockIdx.x*256 + threadIdx.x;
  if (i < NE) atomicAdd(&cursor[dst[i]], 1);
}

__global__ __launch_bounds__(256) void k_scan_a(const int* __restrict__ deg, int* __restrict__ bsum){
  __shared__ int sh[256];
  int tid = threadIdx.x;
  int i = blockIdx.x*256 + tid;
  sh[tid] = (i < NN) ? deg[i] : 0;
  __syncthreads();
  for (int s = 128; s > 0; s >>= 1){
    if (tid < s) sh[tid] += sh[tid+s];
    __syncthreads();
  }
  if (tid == 0) bsum[blockIdx.x] = sh[0];
}

__global__ __launch_bounds__(512) void k_scan_b(int* __restrict__ bsum, int* __restrict__ rowptr){
  __shared__ int tmp[512];
  int tid = threadIdx.x;
  int v = (tid < NB_SCAN) ? bsum[tid] : 0;
  tmp[tid] = v;
  __syncthreads();
  for (int off = 1; off < 512; off <<= 1){
    int t = (tid >= off) ? tmp[tid-off] : 0;
    __syncthreads();
    tmp[tid] += t;
    __syncthreads();
  }
  if (tid < NB_SCAN) bsum[tid] = tmp[tid] - v;
  if (tid == 511) rowptr[NN] = tmp[511];
}

// reads cursor (=deg), writes rowptr and resets cursor to the exclusive offset
__global__ __launch_bounds__(256) void k_scan_c(const int* bsum, int* rowptr, int* cursor){
  __shared__ int tmp[256];
  int tid = threadIdx.x;
  int i = blockIdx.x*256 + tid;
  int v = (i < NN) ? cursor[i] : 0;
  tmp[tid] = v;
  __syncthreads();
  for (int off = 1; off < 256; off <<= 1){
    int t = (tid >= off) ? tmp[tid-off] : 0;
    __syncthreads();
    tmp[tid] += t;
    __syncthreads();
  }
  if (i < NN){
    int excl = tmp[tid] - v + bsum[blockIdx.x];
    rowptr[i] = excl;
    cursor[i] = excl;
  }
}

// Merged scatter + permute: pos via atomicAdd (phase 1, LDS), then block-
// cooperative copy: 8 threads/row read eattr COALESCED, write 64B bf16 row
// to ea_csr[pos] (random 64B bursts). ssrc[pos] = src. slot[] eliminated.
__global__ __launch_bounds__(256) void k_scatter(const int* __restrict__ srcp, const int* __restrict__ dstp,
                                                 const float4* __restrict__ eattr4,
                                                 int* __restrict__ cursor,
                                                 int* __restrict__ ssrc,
                                                 unsigned short* __restrict__ ea_csr){
  __shared__ int spos[256];
  int tid = threadIdx.x;
  int i = blockIdx.x*256 + tid;
  int pos = 0;
  if (i < NE){
    int d = dstp[i];
    pos = atomicAdd(&cursor[d], 1);
    ssrc[pos] = srcp[i];
  }
  spos[tid] = pos;
  __syncthreads();
  int chunk = tid & 7;
  int rbase = blockIdx.x*256;
  #pragma unroll
  for (int k = 0; k < 8; ++k){
    int rl = (tid >> 3) + 32*k;
    int r = rbase + rl;
    if (r < NE){
      float4 v = eattr4[(size_t)r*8 + chunk];
      ushort4 o;
      o.x = f2bf(v.x); o.y = f2bf(v.y); o.z = f2bf(v.z); o.w = f2bf(v.w);
      *(ushort4*)(ea_csr + (size_t)spos[rl]*DE + chunk*4) = o;
    }
  }
}

// MFMA linear: xl[n][j] = bf16( b[j] + sum_k x[n][k]*W[k][j] ).
__global__ __launch_bounds__(256) void k_lin(const float* __restrict__ xin, const float* __restrict__ W,
                                             const float* __restrict__ b, unsigned short* __restrict__ xl){
  int lane = threadIdx.x & 63;
  int q = lane & 15, g = lane >> 4;
  int wid = blockIdx.x*(blockDim.x>>6) + (threadIdx.x>>6);
  int nw = gridDim.x*(blockDim.x>>6);
  short8 wb[2][4];
  #pragma unroll
  for (int kk = 0; kk < 2; ++kk)
    #pragma unroll
    for (int j = 0; j < 4; ++j)
      #pragma unroll
      for (int i = 0; i < 8; ++i)
        wb[kk][j][i] = (short)f2bf(W[(32*kk + 8*g + i)*D + 4*q + j]);
  float4 b4 = *(const float4*)(b + 4*q);
  for (int t0 = wid; t0 < NN/16; t0 += nw){
    int n0 = rfl(t0)*16;
    const float* xr = xin + (size_t)(n0 + q)*D + 8*g;
    float4 a0 = *(const float4*)(xr);
    float4 a1 = *(const float4*)(xr + 4);
    float4 a2 = *(const float4*)(xr + 32);
    float4 a3 = *(const float4*)(xr + 36);
    short8 af0, af1;
    af0[0]=(short)f2bf(a0.x); af0[1]=(short)f2bf(a0.y); af0[2]=(short)f2bf(a0.z); af0[3]=(short)f2bf(a0.w);
    af0[4]=(short)f2bf(a1.x); af0[5]=(short)f2bf(a1.y); af0[6]=(short)f2bf(a1.z); af0[7]=(short)f2bf(a1.w);
    af1[0]=(short)f2bf(a2.x); af1[1]=(short)f2bf(a2.y); af1[2]=(short)f2bf(a2.z); af1[3]=(short)f2bf(a2.w);
    af1[4]=(short)f2bf(a3.x); af1[5]=(short)f2bf(a3.y); af1[6]=(short)f2bf(a3.z); af1[7]=(short)f2bf(a3.w);
    f32x4 acc0 = {b4.x, b4.x, b4.x, b4.x};
    f32x4 acc1 = {b4.y, b4.y, b4.y, b4.y};
    f32x4 acc2 = {b4.z, b4.z, b4.z, b4.z};
    f32x4 acc3 = {b4.w, b4.w, b4.w, b4.w};
    acc0 = __builtin_amdgcn_mfma_f32_16x16x32_bf16(af0, wb[0][0], acc0, 0, 0, 0);
    acc1 = __builtin_amdgcn_mfma_f32_16x16x32_bf16(af0, wb[0][1], acc1, 0, 0, 0);
    acc2 = __builtin_amdgcn_mfma_f32_16x16x32_bf16(af0, wb[0][2], acc2, 0, 0, 0);
    acc3 = __builtin_amdgcn_mfma_f32_16x16x32_bf16(af0, wb[0][3], acc3, 0, 0, 0);
    acc0 = __builtin_amdgcn_mfma_f32_16x16x32_bf16(af1, wb[1][0], acc0, 0, 0, 0);
    acc1 = __builtin_amdgcn_mfma_f32_16x16x32_bf16(af1, wb[1][1], acc1, 0, 0, 0);
    acc2 = __builtin_amdgcn_mfma_f32_16x16x32_bf16(af1, wb[1][2], acc2, 0, 0, 0);
    acc3 = __builtin_amdgcn_mfma_f32_16x16x32_bf16(af1, wb[1][3], acc3, 0, 0, 0);
    #pragma unroll
    for (int i = 0; i < 4; ++i){
      ushort4 pk;
      pk.x = f2bf(acc0[i]); pk.y = f2bf(acc1[i]); pk.z = f2bf(acc2[i]); pk.w = f2bf(acc3[i]);
      *(ushort4*)(xl + (size_t)(n0 + 4*g + i)*D + 4*q) = pk;
    }
  }
}

// Fused layer, 4 NODES PER WAVE (one 16-lane group per node).
// MFMA A-tile = 4 edges x 4 consecutive nodes (A-row q -> node q>>2, edge q&3);
// col-permuted B => lane (q,g) gets node g's edges (tile*4+i) at dims 4q..4q+3.
// No cross-group reduction; all shfl stays within 16 lanes.
__global__ __launch_bounds__(256) void k_node(const int* __restrict__ rowptr,
                                              const int* __restrict__ ssrc,
                                              const unsigned short* __restrict__ ea_csr,
                                              const float* __restrict__ We,
                                              const float* __restrict__ att,
                                              const unsigned short* __restrict__ xl,
                                              const float* __restrict__ bias,
                                              float* __restrict__ outp){
  int lane = threadIdx.x & 63;
  int q = lane & 15, g = lane >> 4;
  int wid = blockIdx.x*(blockDim.x>>6) + (threadIdx.x>>6);
  int n0 = wid*4;                       // exact grid: 25000 waves x 4 nodes
  if (n0 >= NN) return;
  short8 wb[4];
  #pragma unroll
  for (int j = 0; j < 4; ++j)
    #pragma unroll
    for (int i = 0; i < 8; ++i)
      wb[j][i] = (short)f2bf(We[(8*g + i)*D + 4*q + j]);
  float4 att4 = *(const float4*)(att + 4*q);
  float4 bi4  = *(const float4*)(bias + 4*q);
  int st_g = rowptr[n0 + g], en_g = rowptr[n0 + g + 1];
  int anode = q >> 2, aoff = q & 3;
  int st_a = rowptr[n0 + anode], en_a = rowptr[n0 + anode + 1];
  int deg = en_g - st_g;
  int dmax = max(deg, __shfl_xor(deg, 16, 64));
  dmax = max(dmax, __shfl_xor(dmax, 32, 64));
  int ntile = (dmax + 3) >> 2;
  ushort4 xdu = *(const ushort4*)(xl + (size_t)(n0 + g)*D + 4*q);
  float xd0 = bf2f(xdu.x), xd1 = bf2f(xdu.y), xd2 = bf2f(xdu.z), xd3 = bf2f(xdu.w);
  float den = 0.f;
  float ac0=0.f, ac1=0.f, ac2=0.f, ac3=0.f;
  float ts0=0.f, ts1=0.f, ts2=0.f, ts3=0.f;
  for (int t = 0; t < ntile; ++t){
    int apos = st_a + t*4 + aoff;
    int arow = (apos < en_a) ? apos : ((en_a > st_a) ? (en_a - 1) : 0);
    short8 a = *(const short8*)(ea_csr + (size_t)arow*DE + 8*g);
    f32x4 d0={0.f,0.f,0.f,0.f}, d1={0.f,0.f,0.f,0.f}, d2={0.f,0.f,0.f,0.f}, d3={0.f,0.f,0.f,0.f};
    d0 = __builtin_amdgcn_mfma_f32_16x16x32_bf16(a, wb[0], d0, 0, 0, 0);
    d1 = __builtin_amdgcn_mfma_f32_16x16x32_bf16(a, wb[1], d1, 0, 0, 0);
    d2 = __builtin_amdgcn_mfma_f32_16x16x32_bf16(a, wb[2], d2, 0, 0, 0);
    d3 = __builtin_amdgcn_mfma_f32_16x16x32_bf16(a, wb[3], d3, 0, 0, 0);
    #pragma unroll
    for (int i = 0; i < 4; ++i){
      int e = st_g + t*4 + i;
      bool valid = (e < en_g);
      int eidx = valid ? e : 0;
      int si = ssrc[eidx];                                   // 16-lane broadcast
      ushort4 xu = *(const ushort4*)(xl + (size_t)si*D + 4*q);
      float x0=bf2f(xu.x), x1=bf2f(xu.y), x2=bf2f(xu.z), x3=bf2f(xu.w);
      float t0 = d0[i], t1 = d1[i], t2 = d2[i], t3 = d3[i];
      float part = att4.x*LEAKY(x0+xd0+t0);
      part = fmaf(att4.y, LEAKY(x1+xd1+t1), part);
      part = fmaf(att4.z, LEAKY(x2+xd2+t2), part);
      part = fmaf(att4.w, LEAKY(x3+xd3+t3), part);
      part += __shfl_xor(part, 1, 64);
      part += __shfl_xor(part, 2, 64);
      part += __shfl_xor(part, 4, 64);
      part += __shfl_xor(part, 8, 64);
      float c = valid ? part : -1e30f;
      float p = __expf(c);
      den += p;
      if (valid){ ts0 += t0; ts1 += t1; ts2 += t2; ts3 += t3; }
      ac0 = fmaf(p, x0, ac0); ac1 = fmaf(p, x1, ac1);
      ac2 = fmaf(p, x2, ac2); ac3 = fmaf(p, x3, ac3);
    }
  }
  // self loop: t_self = mean(t) by linearity; 0 for isolated nodes
  float inv = 1.f / fmaxf((float)deg, 1.f);
  float s0 = fmaf(ts0, inv, xd0 + xd0);
  float s1 = fmaf(ts1, inv, xd1 + xd1);
  float s2 = fmaf(ts2, inv, xd2 + xd2);
  float s3 = fmaf(ts3, inv, xd3 + xd3);
  float cs = att4.x*LEAKY(s0);
  cs = fmaf(att4.y, LEAKY(s1), cs);
  cs = fmaf(att4.z, LEAKY(s2), cs);
  cs = fmaf(att4.w, LEAKY(s3), cs);
  cs += __shfl_xor(cs, 1, 64);
  cs += __shfl_xor(cs, 2, 64);
  cs += __shfl_xor(cs, 4, 64);
  cs += __shfl_xor(cs, 8, 64);
  float ps = __expf(cs);
  den += ps;
  ac0 = fmaf(ps, xd0, ac0); ac1 = fmaf(ps, xd1, ac1);
  ac2 = fmaf(ps, xd2, ac2); ac3 = fmaf(ps, xd3, ac3);
  float4 o;
  float dinv = 1.f / den;
  o.x = fmaf(ac0, dinv, bi4.x);
  o.y = fmaf(ac1, dinv, bi4.y);
  o.z = fmaf(ac2, dinv, bi4.z);
  o.w = fmaf(ac3, dinv, bi4.w);
  *(float4*)(outp + (size_t)(n0 + g)*D + 4*q) = o;   // all 4 groups write their node
}

extern "C" void kernel_launch(void* const* d_in, const int* in_sizes, int n_in,
                              void* d_out, int out_size, void* d_ws, size_t ws_size,
                              hipStream_t stream){
  const float* x     = (const float*)d_in[0];
  const int*   ei    = (const int*)d_in[1];
  const float* eattr = (const float*)d_in[2];
  const float* W1    = (const float*)d_in[3];
  const float* b1    = (const float*)d_in[4];
  const float* We1   = (const float*)d_in[5];
  const float* att1  = (const float*)d_in[6];
  const float* bias1 = (const float*)d_in[7];
  const float* W2    = (const float*)d_in[8];
  const float* b2    = (const float*)d_in[9];
  const float* We2   = (const float*)d_in[10];
  const float* att2  = (const float*)d_in[11];
  const float* bias2 = (const float*)d_in[12];
  const int* srcp = ei;
  const int* dstp = ei + NE;
  float* out = (float*)d_out;

  char* p = (char*)d_ws;
  size_t off = 0;
  auto alloc = [&](size_t bytes)->char*{
    char* r = p + off; off = (off + bytes + 255) & ~(size_t)255; return r;
  };
  int* rowptr   = (int*)alloc((size_t)(NN+1)*4);
  int* cursor   = (int*)alloc((size_t)NN*4);       // also deg accumulator
  int* bsum     = (int*)alloc(512*4);
  int* ssrc     = (int*)alloc((size_t)NE*4);
  unsigned short* xl = (unsigned short*)alloc((size_t)NN*D*2);  // bf16 rows
  float* h      = (float*)alloc((size_t)NN*D*4);
  unsigned short* ea_csr = (unsigned short*)alloc((size_t)NE*DE*2);  // 102.4 MB bf16

  hipMemsetAsync(cursor, 0, (size_t)NN*4, stream);
  k_deg     <<<(NE+255)/256, 256, 0, stream>>>(dstp, cursor);
  k_scan_a  <<<NB_SCAN, 256, 0, stream>>>(cursor, bsum);
  k_scan_b  <<<1, 512, 0, stream>>>(bsum, rowptr);
  k_scan_c  <<<NB_SCAN, 256, 0, stream>>>(bsum, rowptr, cursor);
  k_scatter <<<NE/256, 256, 0, stream>>>(srcp, dstp, (const float4*)eattr, cursor, ssrc, ea_csr);

  // layer 1
  k_lin <<<1600, 256, 0, stream>>>(x, W1, b1, xl);
  k_node<<<6250, 256, 0, stream>>>(rowptr, ssrc, ea_csr, We1, att1, xl, bias1, h);
  // layer 2
  k_lin <<<1600, 256, 0, stream>>>(h, W2, b2, xl);
  k_node<<<6250, 256, 0, stream>>>(rowptr, ssrc, ea_csr, We2, att2, xl, bias2, out);
}